// Round 7
// baseline (612.085 us; speedup 1.0000x reference)
//
#include <hip/hip_runtime.h>
#include <math.h>

// Problem constants
#define N_ROWS   131072      // 32*64*64 pixels
#define DIM      64
#define KCODES   1024
#define HWSZ     4096
#define CHW      262144
#define OUT_ELEMS 8388608

#define TH        2e-4f      // near-tie threshold: ref fp32 noise (~8e-6) + 2x approx err (~6e-5) + margin
#define FB_BLOCKS 256

// d_ws layout (bytes)
#define WS_WSUM   0              // f32[1024]
#define WS_WH     4096           // ushort[65536] permuted bf16 codebook
#define WS_AIDX   135168         // int[131072] argmin (sweep writes, fallback overwrites)
#define WS_CNT    659456         // u32 flagged-row counter (memset 0 per launch)
#define WS_LIST   659520         // u32[131072] flagged rows (capacity = all rows: no overflow)
#define WS_BLOSS  1183808        // f32[512] loss partials

typedef __attribute__((ext_vector_type(8)))  short bf16x8;
typedef __attribute__((ext_vector_type(16))) float f32x16;

// ---------------------------------------------------------------------------
static __device__ __forceinline__ unsigned short f32_to_bf16(float f) {
    union { float f; unsigned u; } v; v.f = f;
    unsigned r = v.u + 0x7FFFu + ((v.u >> 16) & 1u);   // RNE
    return (unsigned short)(r >> 16);
}
static __device__ __forceinline__ float bf16_to_f32(unsigned short h) {
    union { unsigned u; float f; } v; v.u = ((unsigned)h) << 16;
    return v.f;
}

// numpy pairwise sum of squares, n=64 — bit-exact np.sum(v**2, axis=-1)
__device__ __forceinline__ float np_sumsq64(const float* v) {
#pragma clang fp contract(off)
    float r[8];
#pragma unroll
    for (int j = 0; j < 8; ++j) r[j] = v[j] * v[j];
#pragma unroll
    for (int i = 8; i < 64; i += 8) {
#pragma unroll
        for (int j = 0; j < 8; ++j) {
            float p = v[i + j] * v[i + j];
            r[j] = r[j] + p;
        }
    }
    float s01 = r[0] + r[1], s23 = r[2] + r[3];
    float s45 = r[4] + r[5], s67 = r[6] + r[7];
    return (s01 + s23) + (s45 + s67);
}

// ---------------------------------------------------------------------------
// Kernel A: wsum (np-pairwise, bit-exact b_k) + bf16 codebook pre-permuted
// into MFMA B-fragment order so the sweep stages with a linear copy.
// ---------------------------------------------------------------------------
__global__ __launch_bounds__(256) void vq_prep(const float* __restrict__ w,
                                               float* __restrict__ wsum,
                                               unsigned short* __restrict__ whp) {
    int k = blockIdx.x * 256 + threadIdx.x;   // grid 4*256 = 1024
    const float* wr = w + k * DIM;
    float wv[DIM];
#pragma unroll
    for (int d = 0; d < DIM; ++d) wv[d] = wr[d];
    wsum[k] = np_sumsq64(wv);
    const int tile = k >> 8, cc = (k >> 5) & 7, cl = k & 31;
    unsigned short* base = whp + (size_t)tile * 16384;
#pragma unroll
    for (int p = 0; p < 8; ++p) {
        const int kc = p >> 1, q2 = p & 1;
        unsigned short* dst = base + (((cc * 4 + kc) * 64) + q2 * 32 + cl) * 8;
#pragma unroll
        for (int j = 0; j < 8; ++j) dst[j] = f32_to_bf16(wv[kc * 16 + q2 * 8 + j]);
    }
}

// ---------------------------------------------------------------------------
// Kernel B: single-phase MFMA sweep. 1024 blocks x 256 thr; 128 rows/block,
// 32 rows/wave (32x32x16 bf16, x split hi+lo bf16). Tracks exact global
// top-2 per row; gap < TH -> row appended to fallback list (one lane/row).
// launch_bounds(256,4): VGPR<=128 -> 4 blocks/CU (LDS 33KB*4 fits 160KB).
// ---------------------------------------------------------------------------
__global__ __launch_bounds__(256, 4) void vq_sweep(
        const float* __restrict__ inp,
        const float* __restrict__ wsum,
        const unsigned short* __restrict__ whp,
        int* __restrict__ aidx,
        unsigned int* __restrict__ cnt,
        unsigned int* __restrict__ list) {
    __shared__ unsigned short swt[2048 * 8];   // 32 KB B-tile (frag-interleaved)
    __shared__ float sws[256];                 // 1 KB wsum tile

    const int tid  = threadIdx.x;
    const int lane = tid & 63;
    const int wid  = tid >> 6;         // 0..3
    const int m    = lane & 31;
    const int q    = lane >> 5;        // 0/1
    const int row0 = blockIdx.x * 128;
    const int b    = row0 >> 12;       // block never crosses batch
    const int hw0  = row0 & 4095;

    // ---- A-frags straight from global (coalesced dwords, once) ----
    bf16x8 ah[4], al[4];
    {
        const float* src = inp + (size_t)b * CHW + hw0 + wid * 32 + m;
#pragma unroll
        for (int kc = 0; kc < 4; ++kc) {
            bf16x8 h, l;
#pragma unroll
            for (int j = 0; j < 8; ++j) {
                const int d = kc * 16 + q * 8 + j;
                float xv = src[(size_t)d * HWSZ];
                unsigned short hh = f32_to_bf16(xv);
                float rem = xv - bf16_to_f32(hh);
                h[j] = (short)hh;
                l[j] = (short)f32_to_bf16(rem);
            }
            ah[kc] = h; al[kc] = l;
        }
    }

    float best[16], sec[16];
    int   bidx[16];
#pragma unroll
    for (int r = 0; r < 16; ++r) { best[r] = 1e30f; sec[r] = 1e30f; bidx[r] = 0; }

    for (int tile = 0; tile < 4; ++tile) {
        __syncthreads();
        {   // linear staging (codebook pre-permuted): 16B/lane copy
            const uint4* gsrc = (const uint4*)(whp + (size_t)tile * 16384);
            uint4* ldst = (uint4*)swt;
#pragma unroll
            for (int i = 0; i < 8; ++i)
                ldst[i * 256 + tid] = gsrc[i * 256 + tid];
            sws[tid] = wsum[tile * 256 + tid];
        }
        __syncthreads();

        for (int cc = 0; cc < 8; ++cc) {
            bf16x8 bf[4];
#pragma unroll
            for (int kc = 0; kc < 4; ++kc)
                bf[kc] = *(const bf16x8*)(swt + ((cc * 4 + kc) * 64 + lane) * 8);
            f32x16 acc0 = {0.f}, acc1 = {0.f};
            acc0 = __builtin_amdgcn_mfma_f32_32x32x16_bf16(ah[0], bf[0], acc0, 0, 0, 0);
            acc1 = __builtin_amdgcn_mfma_f32_32x32x16_bf16(ah[1], bf[1], acc1, 0, 0, 0);
            acc0 = __builtin_amdgcn_mfma_f32_32x32x16_bf16(ah[2], bf[2], acc0, 0, 0, 0);
            acc1 = __builtin_amdgcn_mfma_f32_32x32x16_bf16(ah[3], bf[3], acc1, 0, 0, 0);
            acc0 = __builtin_amdgcn_mfma_f32_32x32x16_bf16(al[0], bf[0], acc0, 0, 0, 0);
            acc1 = __builtin_amdgcn_mfma_f32_32x32x16_bf16(al[1], bf[1], acc1, 0, 0, 0);
            acc0 = __builtin_amdgcn_mfma_f32_32x32x16_bf16(al[2], bf[2], acc0, 0, 0, 0);
            acc1 = __builtin_amdgcn_mfma_f32_32x32x16_bf16(al[3], bf[3], acc1, 0, 0, 0);

            const float wsv  = sws[cc * 32 + m];
            const int  kcode = tile * 256 + cc * 32 + m;
#pragma unroll
            for (int r = 0; r < 16; ++r) {
                float v = acc0[r] + acc1[r];
                float t = __builtin_fmaf(v, -2.0f, wsv);
                bool  c = t < best[r];
                sec[r]  = fminf(sec[r], fmaxf(t, best[r]));
                best[r] = fminf(best[r], t);
                bidx[r] = c ? kcode : bidx[r];
            }
        }
    }

    // ---- cross-lane merge over the 32 code-classes (exact global top-2) ----
#pragma unroll
    for (int ms = 1; ms <= 16; ms <<= 1) {
#pragma unroll
        for (int r = 0; r < 16; ++r) {
            float ob = __shfl_xor(best[r], ms, 64);
            float os = __shfl_xor(sec[r],  ms, 64);
            int   oi = __shfl_xor(bidx[r], ms, 64);
            sec[r]  = fminf(fminf(sec[r], os), fmaxf(best[r], ob));
            bool  c = ob < best[r];
            best[r] = fminf(best[r], ob);
            bidx[r] = c ? oi : bidx[r];
        }
    }

    // ---- write idx; flag near-tie rows (lane m==r: one lane per row) ----
    if (m < 16) {
        const int r  = m;
        const int rr = row0 + wid * 32 + (r & 3) + 8 * (r >> 2) + 4 * q;
        aidx[rr] = bidx[r];
        if (sec[r] - best[r] < TH) {
            unsigned pos = atomicAdd(cnt, 1u);
            list[pos] = (unsigned)rr;   // capacity = N_ROWS: cannot overflow
        }
    }
}

// ---------------------------------------------------------------------------
// Kernel C: exact fallback — one WAVE per flagged row, all 1024 codes,
// bit-exact reference emulation; packed-key wave-min (first-index ties).
// launch_bounds(256,2): VGPR budget 256 so x[64] stays register-resident
// (round-6 failure: default cap -> 52 VGPRs -> x spilled to scratch).
// ---------------------------------------------------------------------------
__global__ __launch_bounds__(256, 2) void vq_exact_rows(
        const float* __restrict__ inp,
        const float* __restrict__ weight,
        const float* __restrict__ wsum,
        const unsigned int* __restrict__ cnt_ptr,
        const unsigned int* __restrict__ list,
        int* __restrict__ aidx) {
    __shared__ float sa[128 * 65];   // 33.25 KB padded fp32 code tile
    const int tid  = threadIdx.x;
    const int lane = tid & 63;
    const int wid  = tid >> 6;
    const unsigned cnt = *cnt_ptr;

    for (unsigned base = blockIdx.x * 4u; base < cnt; base += FB_BLOCKS * 4u) {
        const unsigned ridx = base + (unsigned)wid;
        const bool valid = ridx < cnt;
        int row = valid ? (int)list[ridx] : 0;

        float x[DIM];
        float a = 0.f;
        {
            const int rb = row >> 12, rhw = row & 4095;
            const float* xb = inp + (size_t)rb * CHW + rhw;
#pragma unroll
            for (int d = 0; d < DIM; ++d) x[d] = xb[(size_t)d * HWSZ];
            a = np_sumsq64(x);
        }

        unsigned long long key = ~0ull;
        for (int t = 0; t < 8; ++t) {
            __syncthreads();
            for (int i = tid; i < 128 * DIM; i += 256) {
                const int code = i >> 6, d = i & 63;
                sa[code * 65 + d] = weight[(size_t)(t * 128 + code) * DIM + d];
            }
            __syncthreads();
#pragma unroll
            for (int c = 0; c < 2; ++c) {
                const int code = lane * 2 + c;
                const float* wr2 = sa + code * 65;
                float cacc = 0.f;
#pragma unroll
                for (int d = 0; d < DIM; ++d)
                    cacc = __builtin_fmaf(x[d], wr2[d], cacc);
                float s, dk;
                {
#pragma clang fp contract(off)
                    s  = a + wsum[t * 128 + code];
                    dk = s - 2.0f * cacc;
                }
                const int kg = t * 128 + code;
                unsigned long long kv =
                    (((unsigned long long)__float_as_uint(dk)) << 32) | (unsigned)kg;
                key = kv < key ? kv : key;   // dk>0: fp32 bits monotone
            }
        }
        // wave-reduce min key
#pragma unroll
        for (int off = 1; off < 64; off <<= 1) {
            unsigned long long o =
                (unsigned long long)__shfl_xor((long long)key, off, 64);
            key = o < key ? o : key;
        }
        if (valid && lane == 0) aidx[row] = (int)(key & 1023ull);
    }
}

// ---------------------------------------------------------------------------
// Kernel D: epilogue — gather w[aidx], write out NCHW, idx, loss partials
// ---------------------------------------------------------------------------
__global__ __launch_bounds__(256) void vq_epilogue(
        const float* __restrict__ inp,
        const float* __restrict__ weight,
        const int* __restrict__ aidx,
        float* __restrict__ out,
        float* __restrict__ idx_out,
        float* __restrict__ block_loss) {
    const int n  = blockIdx.x * 256 + threadIdx.x;   // grid exact: 512*256
    const int b  = n >> 12;
    const int hw = n & 4095;
    const int k  = aidx[n];

    const float* xb = inp + (size_t)b * CHW + hw;
    const float* wr = weight + k * DIM;
    float* ob = out + (size_t)b * CHW + hw;
    float ls = 0.f;
#pragma unroll
    for (int d = 0; d < DIM; ++d) {
        const float wv = wr[d];
        const float xv = xb[(size_t)d * HWSZ];
        ob[(size_t)d * HWSZ] = wv;
        const float df = wv - xv;
        ls = fmaf(df, df, ls);
    }
    idx_out[n] = (float)k;

    __shared__ float red[4];
#pragma unroll
    for (int off = 32; off > 0; off >>= 1) ls += __shfl_down(ls, off, 64);
    const int lane = threadIdx.x & 63;
    const int wid  = threadIdx.x >> 6;
    if (lane == 0) red[wid] = ls;
    __syncthreads();
    if (threadIdx.x == 0)
        block_loss[blockIdx.x] = (red[0] + red[1]) + (red[2] + red[3]);
}

// ---------------------------------------------------------------------------
// Kernel E: reduce 512 partials -> loss = 1.25 * mean((q-x)^2)
// ---------------------------------------------------------------------------
__global__ __launch_bounds__(256) void vq_loss_reduce(const float* __restrict__ bl,
                                                      float* __restrict__ loss_out) {
    double s = 0.0;
    for (int i = threadIdx.x; i < 512; i += 256) s += (double)bl[i];
    __shared__ double red[4];
#pragma unroll
    for (int off = 32; off > 0; off >>= 1) s += __shfl_down(s, off, 64);
    const int lane = threadIdx.x & 63;
    const int wid  = threadIdx.x >> 6;
    if (lane == 0) red[wid] = s;
    __syncthreads();
    if (threadIdx.x == 0) {
        const double total = (red[0] + red[1]) + (red[2] + red[3]);
        loss_out[0] = (float)(1.25 * total / (double)OUT_ELEMS);
    }
}

// ---------------------------------------------------------------------------
extern "C" void kernel_launch(void* const* d_in, const int* in_sizes, int n_in,
                              void* d_out, int out_size, void* d_ws, size_t ws_size,
                              hipStream_t stream) {
    const float* inp    = (const float*)d_in[0];
    const float* weight = (const float*)d_in[1];

    float* out_q    = (float*)d_out;
    float* out_loss = (float*)d_out + OUT_ELEMS;
    float* out_idx  = (float*)d_out + OUT_ELEMS + 1;

    char* ws = (char*)d_ws;
    float*          wsum  = (float*)(ws + WS_WSUM);
    unsigned short* whp   = (unsigned short*)(ws + WS_WH);
    int*            aidx  = (int*)(ws + WS_AIDX);
    unsigned int*   cnt   = (unsigned int*)(ws + WS_CNT);
    unsigned int*   list  = (unsigned int*)(ws + WS_LIST);
    float*          bloss = (float*)(ws + WS_BLOSS);

    vq_prep<<<4, 256, 0, stream>>>(weight, wsum, whp);
    hipMemsetAsync(cnt, 0, sizeof(unsigned int), stream);
    vq_sweep<<<1024, 256, 0, stream>>>(inp, wsum, whp, aidx, cnt, list);
    vq_exact_rows<<<FB_BLOCKS, 256, 0, stream>>>(inp, weight, wsum, cnt, list, aidx);
    vq_epilogue<<<512, 256, 0, stream>>>(inp, weight, aidx, out_q, out_idx, bloss);
    vq_loss_reduce<<<1, 256, 0, stream>>>(bloss, out_loss);
}

// Round 8
// 553.184 us; speedup vs baseline: 1.1065x; 1.1065x over previous
//
#include <hip/hip_runtime.h>
#include <math.h>

// Problem constants
#define N_ROWS   131072      // 32*64*64 pixels
#define DIM      64
#define KCODES   1024
#define HWSZ     4096
#define CHW      262144
#define OUT_ELEMS 8388608

#define TH        2e-4f      // near-tie threshold: ref fp32 noise + 2x bf16-split max err + margin
#define FB_BLOCKS 256

// d_ws layout (bytes)
#define WS_WSUM   0              // f32[1024]
#define WS_WH     4096           // ushort[65536] permuted bf16 codebook
#define WS_AIDX   135168         // int[131072] argmin (sweep writes, fallback overwrites)
#define WS_CNT    659456         // u32 flagged-row counter (memset 0 per launch)
#define WS_LIST   659520         // u32[131072] flagged rows (capacity = all rows: no overflow)
#define WS_BLOSS  1183808        // f32[512] loss partials

typedef __attribute__((ext_vector_type(8)))  short bf16x8;
typedef __attribute__((ext_vector_type(16))) float f32x16;

// ---------------------------------------------------------------------------
static __device__ __forceinline__ unsigned short f32_to_bf16(float f) {
    union { float f; unsigned u; } v; v.f = f;
    unsigned r = v.u + 0x7FFFu + ((v.u >> 16) & 1u);   // RNE
    return (unsigned short)(r >> 16);
}
static __device__ __forceinline__ float bf16_to_f32(unsigned short h) {
    union { unsigned u; float f; } v; v.u = ((unsigned)h) << 16;
    return v.f;
}

// numpy pairwise sum of squares, n=64 — bit-exact np.sum(v**2, axis=-1)
__device__ __forceinline__ float np_sumsq64(const float* v) {
#pragma clang fp contract(off)
    float r[8];
#pragma unroll
    for (int j = 0; j < 8; ++j) r[j] = v[j] * v[j];
#pragma unroll
    for (int i = 8; i < 64; i += 8) {
#pragma unroll
        for (int j = 0; j < 8; ++j) {
            float p = v[i + j] * v[i + j];
            r[j] = r[j] + p;
        }
    }
    float s01 = r[0] + r[1], s23 = r[2] + r[3];
    float s45 = r[4] + r[5], s67 = r[6] + r[7];
    return (s01 + s23) + (s45 + s67);
}

// ---------------------------------------------------------------------------
// Kernel A: wsum (np-pairwise, bit-exact b_k) + bf16 codebook pre-permuted
// into MFMA B-fragment order so the sweep stages with a linear copy.
// ---------------------------------------------------------------------------
__global__ __launch_bounds__(256) void vq_prep(const float* __restrict__ w,
                                               float* __restrict__ wsum,
                                               unsigned short* __restrict__ whp) {
    int k = blockIdx.x * 256 + threadIdx.x;   // grid 4*256 = 1024
    const float* wr = w + k * DIM;
    float wv[DIM];
#pragma unroll
    for (int d = 0; d < DIM; ++d) wv[d] = wr[d];
    wsum[k] = np_sumsq64(wv);
    const int tile = k >> 8, cc = (k >> 5) & 7, cl = k & 31;
    unsigned short* base = whp + (size_t)tile * 16384;
#pragma unroll
    for (int p = 0; p < 8; ++p) {
        const int kc = p >> 1, q2 = p & 1;
        unsigned short* dst = base + (((cc * 4 + kc) * 64) + q2 * 32 + cl) * 8;
#pragma unroll
        for (int j = 0; j < 8; ++j) dst[j] = f32_to_bf16(wv[kc * 16 + q2 * 8 + j]);
    }
}

// ---------------------------------------------------------------------------
// Kernel B: single-phase MFMA sweep. 1024 blocks x 256 thr; 128 rows/block,
// 32 rows/wave (32x32x16 bf16, x split hi+lo bf16). Tracks exact global
// top-2 per row; gap < TH -> row appended to fallback list (one lane/row).
// (256,3): ~170 VGPR cap — kernel needs ~130, no spill (round-7's (256,4)
// capped at 128 and spilled -> +60us; do not tighten).
// ---------------------------------------------------------------------------
__global__ __launch_bounds__(256, 3) void vq_sweep(
        const float* __restrict__ inp,
        const float* __restrict__ wsum,
        const unsigned short* __restrict__ whp,
        int* __restrict__ aidx,
        unsigned int* __restrict__ cnt,
        unsigned int* __restrict__ list) {
    __shared__ unsigned short swt[2048 * 8];   // 32 KB B-tile (frag-interleaved)
    __shared__ float sws[256];                 // 1 KB wsum tile

    const int tid  = threadIdx.x;
    const int lane = tid & 63;
    const int wid  = tid >> 6;         // 0..3
    const int m    = lane & 31;
    const int q    = lane >> 5;        // 0/1
    const int row0 = blockIdx.x * 128;
    const int b    = row0 >> 12;       // block never crosses batch
    const int hw0  = row0 & 4095;

    // ---- A-frags straight from global (coalesced dwords, once) ----
    bf16x8 ah[4], al[4];
    {
        const float* src = inp + (size_t)b * CHW + hw0 + wid * 32 + m;
#pragma unroll
        for (int kc = 0; kc < 4; ++kc) {
            bf16x8 h, l;
#pragma unroll
            for (int j = 0; j < 8; ++j) {
                const int d = kc * 16 + q * 8 + j;
                float xv = src[(size_t)d * HWSZ];
                unsigned short hh = f32_to_bf16(xv);
                float rem = xv - bf16_to_f32(hh);
                h[j] = (short)hh;
                l[j] = (short)f32_to_bf16(rem);
            }
            ah[kc] = h; al[kc] = l;
        }
    }

    float best[16], sec[16];
    int   bidx[16];
#pragma unroll
    for (int r = 0; r < 16; ++r) { best[r] = 1e30f; sec[r] = 1e30f; bidx[r] = 0; }

    for (int tile = 0; tile < 4; ++tile) {
        __syncthreads();
        {   // linear staging (codebook pre-permuted): 16B/lane copy
            const uint4* gsrc = (const uint4*)(whp + (size_t)tile * 16384);
            uint4* ldst = (uint4*)swt;
#pragma unroll
            for (int i = 0; i < 8; ++i)
                ldst[i * 256 + tid] = gsrc[i * 256 + tid];
            sws[tid] = wsum[tile * 256 + tid];
        }
        __syncthreads();

        for (int cc = 0; cc < 8; ++cc) {
            bf16x8 bf[4];
#pragma unroll
            for (int kc = 0; kc < 4; ++kc)
                bf[kc] = *(const bf16x8*)(swt + ((cc * 4 + kc) * 64 + lane) * 8);
            f32x16 acc0 = {0.f}, acc1 = {0.f};
            acc0 = __builtin_amdgcn_mfma_f32_32x32x16_bf16(ah[0], bf[0], acc0, 0, 0, 0);
            acc1 = __builtin_amdgcn_mfma_f32_32x32x16_bf16(ah[1], bf[1], acc1, 0, 0, 0);
            acc0 = __builtin_amdgcn_mfma_f32_32x32x16_bf16(ah[2], bf[2], acc0, 0, 0, 0);
            acc1 = __builtin_amdgcn_mfma_f32_32x32x16_bf16(ah[3], bf[3], acc1, 0, 0, 0);
            acc0 = __builtin_amdgcn_mfma_f32_32x32x16_bf16(al[0], bf[0], acc0, 0, 0, 0);
            acc1 = __builtin_amdgcn_mfma_f32_32x32x16_bf16(al[1], bf[1], acc1, 0, 0, 0);
            acc0 = __builtin_amdgcn_mfma_f32_32x32x16_bf16(al[2], bf[2], acc0, 0, 0, 0);
            acc1 = __builtin_amdgcn_mfma_f32_32x32x16_bf16(al[3], bf[3], acc1, 0, 0, 0);

            const float wsv  = sws[cc * 32 + m];
            const int  kcode = tile * 256 + cc * 32 + m;
#pragma unroll
            for (int r = 0; r < 16; ++r) {
                float v = acc0[r] + acc1[r];
                float t = __builtin_fmaf(v, -2.0f, wsv);
                bool  c = t < best[r];
                sec[r]  = fminf(sec[r], fmaxf(t, best[r]));
                best[r] = fminf(best[r], t);
                bidx[r] = c ? kcode : bidx[r];
            }
        }
    }

    // ---- cross-lane merge over the 32 code-classes (exact global top-2) ----
#pragma unroll
    for (int ms = 1; ms <= 16; ms <<= 1) {
#pragma unroll
        for (int r = 0; r < 16; ++r) {
            float ob = __shfl_xor(best[r], ms, 64);
            float os = __shfl_xor(sec[r],  ms, 64);
            int   oi = __shfl_xor(bidx[r], ms, 64);
            sec[r]  = fminf(fminf(sec[r], os), fmaxf(best[r], ob));
            bool  c = ob < best[r];
            best[r] = fminf(best[r], ob);
            bidx[r] = c ? oi : bidx[r];
        }
    }

    // ---- write idx; flag near-tie rows (one lane per row) ----
    if (m < 16) {
        const int r  = m;
        const int rr = row0 + wid * 32 + (r & 3) + 8 * (r >> 2) + 4 * q;
        aidx[rr] = bidx[r];
        if (sec[r] - best[r] < TH) {
            unsigned pos = atomicAdd(cnt, 1u);
            list[pos] = (unsigned)rr;   // capacity = N_ROWS: cannot overflow
        }
    }
}

// ---------------------------------------------------------------------------
// Kernel C: exact fallback — one WAVE per flagged row, all 1024 codes,
// bit-exact reference emulation. Row's x lives in LDS (per-wave, broadcast
// reads) — rounds 6/7 proved the compiler refuses to keep x[64] in VGPRs
// and re-fetches from global instead; LDS sidesteps its pressure heuristic.
// Lane handles codes {lane, lane+64} per 128-code tile: stride-65 rows give
// all-32-bank 2-way aliasing (free). Packed-key wave-min, first-index ties.
// ---------------------------------------------------------------------------
__global__ __launch_bounds__(256) void vq_exact_rows(
        const float* __restrict__ inp,
        const float* __restrict__ weight,
        const float* __restrict__ wsum,
        const unsigned int* __restrict__ cnt_ptr,
        const unsigned int* __restrict__ list,
        int* __restrict__ aidx) {
    __shared__ float sa[128 * 65];   // 33.25 KB padded fp32 code tile
    __shared__ float sx[4][72];      // per-wave x row (stride 72: 2-way banks)
    const int tid  = threadIdx.x;
    const int lane = tid & 63;
    const int wid  = tid >> 6;
    const unsigned cnt = *cnt_ptr;

    for (unsigned base = blockIdx.x * 4u; base < cnt; base += FB_BLOCKS * 4u) {
        const unsigned ridx = base + (unsigned)wid;
        const bool valid = ridx < cnt;
        const int row = valid ? (int)list[ridx] : 0;

        // stage this wave's x row into LDS (one element per lane)
        {
            const int rb = row >> 12, rhw = row & 4095;
            sx[wid][lane] = inp[(size_t)rb * CHW + rhw + (size_t)lane * HWSZ];
        }
        const float* xv = &sx[wid][0];
        const float a = np_sumsq64(xv);   // broadcast LDS reads, per-lane redundant

        unsigned long long key = ~0ull;
        for (int t = 0; t < 8; ++t) {
            __syncthreads();
            for (int i = tid; i < 128 * DIM; i += 256) {
                const int code = i >> 6, d = i & 63;
                sa[code * 65 + d] = weight[(size_t)(t * 128 + code) * DIM + d];
            }
            __syncthreads();
            // codes k0 = t*128+lane, k1 = t*128+64+lane (k0 < k1)
            const float* w0 = sa + lane * 65;
            const float* w1 = sa + (64 + lane) * 65;
            float c0 = 0.f, c1 = 0.f;
#pragma unroll
            for (int d = 0; d < DIM; ++d) {
                const float xd = xv[d];
                c0 = __builtin_fmaf(xd, w0[d], c0);   // sequential chain, asc d
                c1 = __builtin_fmaf(xd, w1[d], c1);
            }
            float s0, dk0, s1, dk1;
            {
#pragma clang fp contract(off)
                s0  = a + wsum[t * 128 + lane];
                dk0 = s0 - 2.0f * c0;
                s1  = a + wsum[t * 128 + 64 + lane];
                dk1 = s1 - 2.0f * c1;
            }
            const unsigned k0 = (unsigned)(t * 128 + lane);
            unsigned long long kv0 =
                (((unsigned long long)__float_as_uint(dk0)) << 32) | k0;
            unsigned long long kv1 =
                (((unsigned long long)__float_as_uint(dk1)) << 32) | (k0 + 64u);
            key = kv0 < key ? kv0 : key;   // dk>0: fp32 bits monotone
            key = kv1 < key ? kv1 : key;
        }
        // wave-reduce min key
#pragma unroll
        for (int off = 1; off < 64; off <<= 1) {
            unsigned long long o =
                (unsigned long long)__shfl_xor((long long)key, off, 64);
            key = o < key ? o : key;
        }
        if (valid && lane == 0) aidx[row] = (int)(key & 1023ull);
    }
}

// ---------------------------------------------------------------------------
// Kernel D: epilogue — gather w[aidx], write out NCHW, idx, loss partials
// ---------------------------------------------------------------------------
__global__ __launch_bounds__(256) void vq_epilogue(
        const float* __restrict__ inp,
        const float* __restrict__ weight,
        const int* __restrict__ aidx,
        float* __restrict__ out,
        float* __restrict__ idx_out,
        float* __restrict__ block_loss) {
    const int n  = blockIdx.x * 256 + threadIdx.x;   // grid exact: 512*256
    const int b  = n >> 12;
    const int hw = n & 4095;
    const int k  = aidx[n];

    const float* xb = inp + (size_t)b * CHW + hw;
    const float* wr = weight + k * DIM;
    float* ob = out + (size_t)b * CHW + hw;
    float ls = 0.f;
#pragma unroll
    for (int d = 0; d < DIM; ++d) {
        const float wv = wr[d];
        const float xv = xb[(size_t)d * HWSZ];
        ob[(size_t)d * HWSZ] = wv;
        const float df = wv - xv;
        ls = fmaf(df, df, ls);
    }
    idx_out[n] = (float)k;

    __shared__ float red[4];
#pragma unroll
    for (int off = 32; off > 0; off >>= 1) ls += __shfl_down(ls, off, 64);
    const int lane = threadIdx.x & 63;
    const int wid  = threadIdx.x >> 6;
    if (lane == 0) red[wid] = ls;
    __syncthreads();
    if (threadIdx.x == 0)
        block_loss[blockIdx.x] = (red[0] + red[1]) + (red[2] + red[3]);
}

// ---------------------------------------------------------------------------
// Kernel E: reduce 512 partials -> loss = 1.25 * mean((q-x)^2)
// ---------------------------------------------------------------------------
__global__ __launch_bounds__(256) void vq_loss_reduce(const float* __restrict__ bl,
                                                      float* __restrict__ loss_out) {
    double s = 0.0;
    for (int i = threadIdx.x; i < 512; i += 256) s += (double)bl[i];
    __shared__ double red[4];
#pragma unroll
    for (int off = 32; off > 0; off >>= 1) s += __shfl_down(s, off, 64);
    const int lane = threadIdx.x & 63;
    const int wid  = threadIdx.x >> 6;
    if (lane == 0) red[wid] = s;
    __syncthreads();
    if (threadIdx.x == 0) {
        const double total = (red[0] + red[1]) + (red[2] + red[3]);
        loss_out[0] = (float)(1.25 * total / (double)OUT_ELEMS);
    }
}

// ---------------------------------------------------------------------------
extern "C" void kernel_launch(void* const* d_in, const int* in_sizes, int n_in,
                              void* d_out, int out_size, void* d_ws, size_t ws_size,
                              hipStream_t stream) {
    const float* inp    = (const float*)d_in[0];
    const float* weight = (const float*)d_in[1];

    float* out_q    = (float*)d_out;
    float* out_loss = (float*)d_out + OUT_ELEMS;
    float* out_idx  = (float*)d_out + OUT_ELEMS + 1;

    char* ws = (char*)d_ws;
    float*          wsum  = (float*)(ws + WS_WSUM);
    unsigned short* whp   = (unsigned short*)(ws + WS_WH);
    int*            aidx  = (int*)(ws + WS_AIDX);
    unsigned int*   cnt   = (unsigned int*)(ws + WS_CNT);
    unsigned int*   list  = (unsigned int*)(ws + WS_LIST);
    float*          bloss = (float*)(ws + WS_BLOSS);

    vq_prep<<<4, 256, 0, stream>>>(weight, wsum, whp);
    hipMemsetAsync(cnt, 0, sizeof(unsigned int), stream);
    vq_sweep<<<1024, 256, 0, stream>>>(inp, wsum, whp, aidx, cnt, list);
    vq_exact_rows<<<FB_BLOCKS, 256, 0, stream>>>(inp, weight, wsum, cnt, list, aidx);
    vq_epilogue<<<512, 256, 0, stream>>>(inp, weight, aidx, out_q, out_idx, bloss);
    vq_loss_reduce<<<1, 256, 0, stream>>>(bloss, out_loss);
}